// Round 3
// baseline (96.897 us; speedup 1.0000x reference)
//
#include <hip/hip_runtime.h>
#include <math.h>

#define NQ 6
#define DIM 64
#define W1S 65           // padded LDS stride
#define NB 4             // elements per wave-iteration
#define PI_F 3.14159265358979323846f

typedef int i32x2 __attribute__((ext_vector_type(2)));

// ---------- DPP helpers ----------
template <int CTRL, int ROWM, bool BC>
__device__ __forceinline__ float dpp_add_src(float v) {
  int r = __builtin_amdgcn_update_dpp(0, __float_as_int(v), CTRL, ROWM, 0xF, BC);
  return __int_as_float(r);
}

// sum over 64 lanes; valid in lane 63
__device__ __forceinline__ float red_sum(float v) {
  v += dpp_add_src<0x111, 0xF, true>(v);   // row_shr:1
  v += dpp_add_src<0x112, 0xF, true>(v);   // row_shr:2
  v += dpp_add_src<0x114, 0xF, true>(v);   // row_shr:4
  v += dpp_add_src<0x118, 0xF, true>(v);   // row_shr:8
  v += dpp_add_src<0x142, 0xA, false>(v);  // row_bcast:15 -> rows 1,3
  v += dpp_add_src<0x143, 0xC, false>(v);  // row_bcast:31 -> rows 2,3
  return v;
}
__device__ __forceinline__ float bcast63(float v) {
  return __int_as_float(__builtin_amdgcn_readlane(__float_as_int(v), 63));
}
__device__ __forceinline__ float rdlane(float v, int l) {
  return __int_as_float(__builtin_amdgcn_readlane(__float_as_int(v), l));
}

// partner across xor-32 on the VALU pipe (permlane32_swap), not LDS
__device__ __forceinline__ float partner32(float v, bool lo32) {
#if __has_builtin(__builtin_amdgcn_permlane32_swap)
  i32x2 r = __builtin_amdgcn_permlane32_swap(__float_as_int(v),
                                             __float_as_int(v), false, false);
  return __int_as_float(lo32 ? r[1] : r[0]);
#else
  return __shfl_xor(v, 32, 64);
#endif
}

// ---------- xor-partner shuffle for wire W>=1 (mask = 32>>W) ----------
template <int W>
__device__ __forceinline__ float sh_partner(float v) {
  if constexpr (W == 5) {        // xor 1: quad_perm [1,0,3,2]
    int i = __float_as_int(v);
    return __int_as_float(__builtin_amdgcn_update_dpp(i, i, 0xB1, 0xF, 0xF, false));
  } else if constexpr (W == 4) { // xor 2: quad_perm [2,3,0,1]
    int i = __float_as_int(v);
    return __int_as_float(__builtin_amdgcn_update_dpp(i, i, 0x4E, 0xF, 0xF, false));
  } else if constexpr (W == 3) { // xor 4
    return __int_as_float(__builtin_amdgcn_ds_swizzle(__float_as_int(v), 0x101F));
  } else if constexpr (W == 2) { // xor 8
    return __int_as_float(__builtin_amdgcn_ds_swizzle(__float_as_int(v), 0x201F));
  } else {                       // xor 16
    return __int_as_float(__builtin_amdgcn_ds_swizzle(__float_as_int(v), 0x401F));
  }
}

// ---------- one Rot gate on wire W applied to NB states; c = (ar,ai,br,bi) ----------
template <int W>
__device__ __forceinline__ void gate4(float (&re)[NB], float (&im)[NB],
                                      float4 c, int lane, bool lo32) {
  const bool hi = (W == 0) ? !lo32 : ((lane & (32 >> W)) != 0);
  const float sa = hi ? -c.y : c.y;
  const float sb = hi ? -c.z : c.z;
  #pragma unroll
  for (int r = 0; r < NB; ++r) {
    float pr, pi;
    if constexpr (W == 0) {
      pr = partner32(re[r], lo32);
      pi = partner32(im[r], lo32);
    } else {
      pr = sh_partner<W>(re[r]);
      pi = sh_partner<W>(im[r]);
    }
    float nr = c.x * re[r];
    nr = fmaf(-sa, im[r], nr);
    nr = fmaf(sb, pr, nr);
    nr = fmaf(-c.w, pi, nr);
    float ni = c.x * im[r];
    ni = fmaf(sa, re[r], ni);
    ni = fmaf(sb, pi, ni);
    ni = fmaf(c.w, pr, ni);
    re[r] = nr; im[r] = ni;
  }
}

__device__ __forceinline__ void sel_layer4(float (&re)[NB], float (&im)[NB],
                                           const float4* cf, int pa,
                                           int lane, bool lo32) {
  gate4<0>(re, im, cf[0], lane, lo32);
  gate4<1>(re, im, cf[1], lane, lo32);
  gate4<2>(re, im, cf[2], lane, lo32);
  gate4<3>(re, im, cf[3], lane, lo32);
  gate4<4>(re, im, cf[4], lane, lo32);
  gate4<5>(re, im, cf[5], lane, lo32);
  #pragma unroll
  for (int r = 0; r < NB; ++r) {
    re[r] = __int_as_float(__builtin_amdgcn_ds_bpermute(pa, __float_as_int(re[r])));
    im[r] = __int_as_float(__builtin_amdgcn_ds_bpermute(pa, __float_as_int(im[r])));
  }
}

// composed source index for the CNOT ring of range r
__device__ __forceinline__ int cnot_src(int j, int r) {
  int i = j;
  #pragma unroll
  for (int w = 5; w >= 0; --w) {
    const int cm = 32 >> w;
    const int tm = 32 >> ((w + r) % NQ);
    if (i & cm) i ^= tm;
  }
  return i;
}

__global__ __launch_bounds__(256, 4) void qmaml_wave4(
    const float* __restrict__ x,
    const float* __restrict__ W1,
    const float* __restrict__ b1,
    const float* __restrict__ ln_g,
    const float* __restrict__ ln_b,
    const float* __restrict__ W2,
    const float* __restrict__ b2,
    const float* __restrict__ th_sh,
    const float* __restrict__ th_tk,
    const float* __restrict__ Wc,
    const float* __restrict__ bc,
    float* __restrict__ out,
    int B)
{
  __shared__ float w1t[64 * W1S];   // W1^T padded: w1t[k*65 + j] = W1[j][k]
  __shared__ float4 coef[18];

  const int tid = threadIdx.x;

  // ---- stage W1^T (coalesced reads, conflict-free writes) ----
  #pragma unroll
  for (int it = 0; it < 16; ++it) {
    int idx = tid + it * 256;
    w1t[(idx & 63) * W1S + (idx >> 6)] = W1[idx];
  }
  // ---- gate coefficient table ----
  if (tid < 18) {
    const int layer = tid / 6, w = tid % 6;
    const float* th = (layer < 2) ? (th_sh + (layer * 6 + w) * 3)
                                  : (th_tk + w * 3);
    const float phi = th[0], the = th[1], om = th[2];
    float S, C;   sincosf(0.5f * the,        &S,  &C);
    float sS, cS; sincosf(0.5f * (om + phi), &sS, &cS);
    float sD, cD; sincosf(0.5f * (om - phi), &sD, &cD);
    coef[tid] = make_float4(C * cS, -C * sS, -S * cD, S * sD);
  }
  __syncthreads();

  const int lane = tid & 63;
  const bool lo32 = lane < 32;
  const int wid = __builtin_amdgcn_readfirstlane(blockIdx.x * 4 + (tid >> 6));
  const int nw = gridDim.x * 4;

  // ---- batch-independent per-lane preloads ----
  const float b1v = b1[lane];
  const float lgv = ln_g[lane];
  const float lbv = ln_b[lane];
  float w2v[NQ];
  #pragma unroll
  for (int m = 0; m < NQ; ++m) w2v[m] = W2[m * DIM + lane];
  const float b2p = (lane < NB * NQ) ? b2[lane % NQ] : 0.0f;  // packed angles
  const float bcv = (lane < 5) ? bc[lane] : 0.0f;
  float g[5];
  #pragma unroll
  for (int j = 0; j < 5; ++j) {
    float a = 0.0f;
    #pragma unroll
    for (int w = 0; w < NQ; ++w) {
      float wc = Wc[j * NQ + w];
      a += (lane & (32 >> w)) ? -wc : wc;
    }
    g[j] = a;
  }
  const int pa1 = cnot_src(lane, 1) << 2;
  const int pa2 = cnot_src(lane, 2) << 2;

  for (int t0 = wid * NB; t0 < B; t0 += nw * NB) {
    // ---- Linear1 + ReLU for NB elements; W1 value read once per k ----
    float acc[NB];
    const float* xp[NB];
    #pragma unroll
    for (int r = 0; r < NB; ++r) {
      int tr = t0 + r; if (tr > B - 1) tr = B - 1;
      xp[r] = x + (size_t)tr * DIM;   // wave-uniform -> SMEM loads
      acc[r] = b1v;
    }
    #pragma unroll
    for (int k = 0; k < DIM; ++k) {
      const float wv = w1t[k * W1S + lane];
      #pragma unroll
      for (int r = 0; r < NB; ++r) acc[r] = fmaf(wv, xp[r][k], acc[r]);
    }

    // ---- LayerNorm (mean & E[x^2] chains run concurrently) ----
    float h[NB];
    #pragma unroll
    for (int r = 0; r < NB; ++r) {
      const float hv = fmaxf(acc[r], 0.0f);
      const float s1 = bcast63(red_sum(hv)) * (1.0f / DIM);
      const float s2 = bcast63(red_sum(hv * hv)) * (1.0f / DIM);
      const float var = s2 - s1 * s1;
      const float rs = __builtin_amdgcn_rsqf(var + 1e-5f);
      h[r] = fmaf((hv - s1) * rs, lgv, lbv);
    }

    // ---- Linear2: pack the NB*6 angle sums into lanes 0..23 ----
    float y = 0.0f;
    #pragma unroll
    for (int m = 0; m < NQ; ++m) {
      #pragma unroll
      for (int r = 0; r < NB; ++r) {
        const float s = bcast63(red_sum(w2v[m] * h[r]));
        y = (lane == r * NQ + m) ? s : y;
      }
    }
    y += b2p;

    // ---- tanh + half-angle sincos, one evaluation for all NB elements ----
    const float e = __expf(2.0f * y);
    const float tz = fmaf(-2.0f, __builtin_amdgcn_rcpf(e + 1.0f), 1.0f);
    const float ha = (0.5f * PI_F) * tz;
    const float sv = __sinf(ha);
    const float cv = __cosf(ha);

    // ---- init product states ----
    float re[NB], im[NB];
    #pragma unroll
    for (int r = 0; r < NB; ++r) {
      float a = (lane & 32) ? rdlane(sv, r * NQ + 0) : rdlane(cv, r * NQ + 0);
      a *= (lane & 16) ? rdlane(sv, r * NQ + 1) : rdlane(cv, r * NQ + 1);
      a *= (lane &  8) ? rdlane(sv, r * NQ + 2) : rdlane(cv, r * NQ + 2);
      a *= (lane &  4) ? rdlane(sv, r * NQ + 3) : rdlane(cv, r * NQ + 3);
      a *= (lane &  2) ? rdlane(sv, r * NQ + 4) : rdlane(cv, r * NQ + 4);
      a *= (lane &  1) ? rdlane(sv, r * NQ + 5) : rdlane(cv, r * NQ + 5);
      re[r] = a;
      im[r] = 0.0f;
    }

    // ---- 3 entangling layers (ranges 1, 2, 1) ----
    sel_layer4(re, im, coef + 0,  pa1, lane, lo32);
    sel_layer4(re, im, coef + 6,  pa2, lane, lo32);
    sel_layer4(re, im, coef + 12, pa1, lane, lo32);

    // ---- measurement + classifier head ----
    #pragma unroll
    for (int r = 0; r < NB; ++r) {
      const float p = fmaf(re[r], re[r], im[r] * im[r]);
      float vout = 0.0f;
      #pragma unroll
      for (int j = 0; j < 5; ++j) {
        const float o = bcast63(red_sum(p * g[j]));
        vout = (lane == j) ? o : vout;
      }
      const int tr = t0 + r;
      if (lane < 5 && tr < B) out[(size_t)tr * 5 + lane] = vout + bcv;
    }
  }
}

extern "C" void kernel_launch(void* const* d_in, const int* in_sizes, int n_in,
                              void* d_out, int out_size, void* d_ws, size_t ws_size,
                              hipStream_t stream) {
  const float* x     = (const float*)d_in[0];
  const float* W1    = (const float*)d_in[1];
  const float* b1    = (const float*)d_in[2];
  const float* ln_g  = (const float*)d_in[3];
  const float* ln_b  = (const float*)d_in[4];
  const float* W2    = (const float*)d_in[5];
  const float* b2    = (const float*)d_in[6];
  const float* th_sh = (const float*)d_in[7];
  const float* th_tk = (const float*)d_in[8];
  const float* Wc    = (const float*)d_in[9];
  const float* bc    = (const float*)d_in[10];
  float* out = (float*)d_out;

  const int B = in_sizes[0] / DIM;
  int blocks = (B + 16 - 1) / 16;    // 4 waves x 4 elements per block-iteration
  if (blocks > 2048) blocks = 2048;
  qmaml_wave4<<<blocks, 256, 0, stream>>>(x, W1, b1, ln_g, ln_b, W2, b2,
                                          th_sh, th_tk, Wc, bc, out, B);
}

// Round 4
// 73.439 us; speedup vs baseline: 1.3194x; 1.3194x over previous
//
#include <hip/hip_runtime.h>
#include <math.h>

#define NQ 6
#define DIM 64
#define NB 2             // elements per wave-iteration
#define PI_F 3.14159265358979323846f

typedef int i32x2 __attribute__((ext_vector_type(2)));

// ---------- DPP helpers ----------
template <int CTRL, int ROWM, bool BC>
__device__ __forceinline__ float dpp_add_src(float v) {
  int r = __builtin_amdgcn_update_dpp(0, __float_as_int(v), CTRL, ROWM, 0xF, BC);
  return __int_as_float(r);
}
// full-exchange data movement (every lane receives a value)
template <int CTRL>
__device__ __forceinline__ float dpp_mov(float v) {
  int i = __float_as_int(v);
  return __int_as_float(__builtin_amdgcn_update_dpp(i, i, CTRL, 0xF, 0xF, false));
}

// sum over 64 lanes; valid in lane 63
__device__ __forceinline__ float red_sum(float v) {
  v += dpp_add_src<0x111, 0xF, true>(v);   // row_shr:1
  v += dpp_add_src<0x112, 0xF, true>(v);   // row_shr:2
  v += dpp_add_src<0x114, 0xF, true>(v);   // row_shr:4
  v += dpp_add_src<0x118, 0xF, true>(v);   // row_shr:8
  v += dpp_add_src<0x142, 0xA, false>(v);  // row_bcast:15 -> rows 1,3
  v += dpp_add_src<0x143, 0xC, false>(v);  // row_bcast:31 -> rows 2,3
  return v;
}
__device__ __forceinline__ float bcast63(float v) {
  return __int_as_float(__builtin_amdgcn_readlane(__float_as_int(v), 63));
}
__device__ __forceinline__ float rdlane(float v, int l) {
  return __int_as_float(__builtin_amdgcn_readlane(__float_as_int(v), l));
}

// ---------- xor-partner exchange for wire W (mask = 32>>W) ----------
template <int W>
__device__ __forceinline__ float shuf(float v, int lane) {
  if constexpr (W == 5) {        // xor 1: quad_perm [1,0,3,2]
    return dpp_mov<0xB1>(v);
  } else if constexpr (W == 4) { // xor 2: quad_perm [2,3,0,1]
    return dpp_mov<0x4E>(v);
  } else if constexpr (W == 3) { // xor 4: LDS swizzle (no DPP/permlane form)
    return __int_as_float(__builtin_amdgcn_ds_swizzle(__float_as_int(v), 0x101F));
  } else if constexpr (W == 2) { // xor 8 == row_ror:8 within 16-lane rows
    return dpp_mov<0x128>(v);
  } else if constexpr (W == 1) { // xor 16: permlane16_swap (VALU)
#if __has_builtin(__builtin_amdgcn_permlane16_swap)
    i32x2 r = __builtin_amdgcn_permlane16_swap(__float_as_int(v),
                                               __float_as_int(v), false, false);
    return __int_as_float((lane & 16) ? r[0] : r[1]);
#else
    return __int_as_float(__builtin_amdgcn_ds_swizzle(__float_as_int(v), 0x401F));
#endif
  } else {                       // xor 32: permlane32_swap (VALU)
#if __has_builtin(__builtin_amdgcn_permlane32_swap)
    i32x2 r = __builtin_amdgcn_permlane32_swap(__float_as_int(v),
                                               __float_as_int(v), false, false);
    return __int_as_float((lane & 32) ? r[0] : r[1]);
#else
    return __shfl_xor(v, 32, 64);
#endif
  }
}

// ---------- one Rot gate on wire W applied to NB states ----------
// U = [[a, b], [-conj(b), conj(a)]]; coefs (ar,ai,br,bi) are wave-uniform;
// sgn = -1 on the |1> half of the wire, +1 on the |0> half.
template <int W>
__device__ __forceinline__ void gateN(float (&re)[NB], float (&im)[NB],
                                      float ar, float ai, float br, float bi,
                                      float sgn, int lane) {
  const float ais = ai * sgn;
  const float brs = br * sgn;
  #pragma unroll
  for (int r = 0; r < NB; ++r) {
    const float pr = shuf<W>(re[r], lane);
    const float pi = shuf<W>(im[r], lane);
    float nr = ar * re[r];
    nr = fmaf(-ais, im[r], nr);
    nr = fmaf(brs, pr, nr);
    nr = fmaf(-bi, pi, nr);
    float ni = ar * im[r];
    ni = fmaf(ais, re[r], ni);
    ni = fmaf(brs, pi, ni);
    ni = fmaf(bi, pr, ni);
    re[r] = nr; im[r] = ni;
  }
}

// composed source index for the CNOT ring of range r
__device__ __forceinline__ int cnot_src(int j, int r) {
  int i = j;
  #pragma unroll
  for (int w = 5; w >= 0; --w) {
    const int cm = 32 >> w;
    const int tm = 32 >> ((w + r) % NQ);
    if (i & cm) i ^= tm;
  }
  return i;
}

template <int BASE>
__device__ __forceinline__ void layerN(float (&re)[NB], float (&im)[NB],
                                       const float (&car)[18], const float (&cai)[18],
                                       const float (&cbr)[18], const float (&cbi)[18],
                                       const float (&sgn)[NQ], int pa, int lane) {
  gateN<0>(re, im, car[BASE+0], cai[BASE+0], cbr[BASE+0], cbi[BASE+0], sgn[0], lane);
  gateN<1>(re, im, car[BASE+1], cai[BASE+1], cbr[BASE+1], cbi[BASE+1], sgn[1], lane);
  gateN<2>(re, im, car[BASE+2], cai[BASE+2], cbr[BASE+2], cbi[BASE+2], sgn[2], lane);
  gateN<3>(re, im, car[BASE+3], cai[BASE+3], cbr[BASE+3], cbi[BASE+3], sgn[3], lane);
  gateN<4>(re, im, car[BASE+4], cai[BASE+4], cbr[BASE+4], cbi[BASE+4], sgn[4], lane);
  gateN<5>(re, im, car[BASE+5], cai[BASE+5], cbr[BASE+5], cbi[BASE+5], sgn[5], lane);
  #pragma unroll
  for (int r = 0; r < NB; ++r) {
    re[r] = __int_as_float(__builtin_amdgcn_ds_bpermute(pa, __float_as_int(re[r])));
    im[r] = __int_as_float(__builtin_amdgcn_ds_bpermute(pa, __float_as_int(im[r])));
  }
}

__global__ __launch_bounds__(256) void qmaml_v4(
    const float* __restrict__ x,
    const float* __restrict__ W1,
    const float* __restrict__ b1,
    const float* __restrict__ ln_g,
    const float* __restrict__ ln_b,
    const float* __restrict__ W2,
    const float* __restrict__ b2,
    const float* __restrict__ th_sh,
    const float* __restrict__ th_tk,
    const float* __restrict__ Wc,
    const float* __restrict__ bc,
    float* __restrict__ out,
    int B)
{
  // W1^T in float4 chunks: w1t4[k4*64 + j] = {W1[j][4k4+0..3]}
  __shared__ float4 w1t4[16 * 64];   // 16 KiB

  const int tid = threadIdx.x;

  #pragma unroll
  for (int it = 0; it < 4; ++it) {
    const int idx = tid + it * 256;          // global float4 index = j*16 + k4
    w1t4[(idx & 15) * 64 + (idx >> 4)] = reinterpret_cast<const float4*>(W1)[idx];
  }
  __syncthreads();

  const int lane = tid & 63;
  const int wid = __builtin_amdgcn_readfirstlane(blockIdx.x * 4 + (tid >> 6));
  const int nw = gridDim.x * 4;

  // ---- gate coefficients: computed once per wave (lanes 0..17), then
  //      extracted to wave-uniform scalars (SGPR-resident, loop-hoisted) ----
  float c0 = 0.f, c1 = 0.f, c2 = 0.f, c3 = 0.f;
  {
    const int g = (lane < 18) ? lane : 0;
    const int layer = g / 6, w = g % 6;
    const float* th = (layer < 2) ? (th_sh + (layer * 6 + w) * 3)
                                  : (th_tk + w * 3);
    const float phi = th[0], the = th[1], om = th[2];
    float S, C;   sincosf(0.5f * the,        &S,  &C);
    float sS, cS; sincosf(0.5f * (om + phi), &sS, &cS);
    float sD, cD; sincosf(0.5f * (om - phi), &sD, &cD);
    c0 = C * cS; c1 = -C * sS; c2 = -S * cD; c3 = S * sD;
  }
  float car[18], cai[18], cbr[18], cbi[18];
  #pragma unroll
  for (int g = 0; g < 18; ++g) {
    car[g] = rdlane(c0, g); cai[g] = rdlane(c1, g);
    cbr[g] = rdlane(c2, g); cbi[g] = rdlane(c3, g);
  }

  // ---- batch-independent per-lane preloads ----
  const float b1v = b1[lane];
  const float lgv = ln_g[lane];
  const float lbv = ln_b[lane];
  float w2v[NQ];
  #pragma unroll
  for (int m = 0; m < NQ; ++m) w2v[m] = W2[m * DIM + lane];
  const float b2p = (lane < NB * NQ) ? b2[lane % NQ] : 0.0f;
  const float bcv = (lane < 5) ? bc[lane] : 0.0f;
  float sgn[NQ];
  #pragma unroll
  for (int w = 0; w < NQ; ++w) sgn[w] = (lane & (32 >> w)) ? -1.0f : 1.0f;
  float g5[5];
  #pragma unroll
  for (int j = 0; j < 5; ++j) {
    float a = 0.0f;
    #pragma unroll
    for (int w = 0; w < NQ; ++w) {
      const float wc = Wc[j * NQ + w];
      a += (lane & (32 >> w)) ? -wc : wc;
    }
    g5[j] = a;
  }
  const int pa1 = cnot_src(lane, 1) << 2;
  const int pa2 = cnot_src(lane, 2) << 2;

  for (int t0 = wid * NB; t0 < B; t0 += nw * NB) {
    // ---- Linear1 + ReLU for NB elements; W1 chunk read once per k4 ----
    const float* __restrict__ xr0 = x + (size_t)t0 * DIM;        // wave-uniform
    const float* __restrict__ xr1 = xr0 + ((t0 + 1 < B) ? DIM : 0);
    float acc[NB] = {b1v, b1v};
    #pragma unroll
    for (int k4 = 0; k4 < 16; ++k4) {
      const float4 wv = w1t4[k4 * 64 + lane];   // contiguous across lanes
      acc[0] = fmaf(wv.x, xr0[4*k4+0], acc[0]);
      acc[0] = fmaf(wv.y, xr0[4*k4+1], acc[0]);
      acc[0] = fmaf(wv.z, xr0[4*k4+2], acc[0]);
      acc[0] = fmaf(wv.w, xr0[4*k4+3], acc[0]);
      acc[1] = fmaf(wv.x, xr1[4*k4+0], acc[1]);
      acc[1] = fmaf(wv.y, xr1[4*k4+1], acc[1]);
      acc[1] = fmaf(wv.z, xr1[4*k4+2], acc[1]);
      acc[1] = fmaf(wv.w, xr1[4*k4+3], acc[1]);
    }

    // ---- LayerNorm (sum & sum-of-squares chains independent) ----
    float h[NB];
    #pragma unroll
    for (int r = 0; r < NB; ++r) {
      const float hv = fmaxf(acc[r], 0.0f);
      const float s1 = bcast63(red_sum(hv)) * (1.0f / DIM);
      const float s2 = bcast63(red_sum(hv * hv)) * (1.0f / DIM);
      const float var = s2 - s1 * s1;
      const float rs = __builtin_amdgcn_rsqf(var + 1e-5f);
      h[r] = fmaf((hv - s1) * rs, lgv, lbv);
    }

    // ---- Linear2: pack the NB*6 angle sums into lanes 0..11 ----
    float y = 0.0f;
    #pragma unroll
    for (int m = 0; m < NQ; ++m) {
      #pragma unroll
      for (int r = 0; r < NB; ++r) {
        const float s = bcast63(red_sum(w2v[m] * h[r]));
        y = (lane == r * NQ + m) ? s : y;
      }
    }
    y += b2p;

    // ---- tanh + half-angle sincos: one evaluation for all NB elements ----
    const float e = __expf(2.0f * y);
    const float tz = fmaf(-2.0f, __builtin_amdgcn_rcpf(e + 1.0f), 1.0f);
    const float ha = (0.5f * PI_F) * tz;
    const float sv = __sinf(ha);
    const float cv = __cosf(ha);

    // ---- init product states (lane = basis index) ----
    float re[NB], im[NB];
    #pragma unroll
    for (int r = 0; r < NB; ++r) {
      float a = (lane & 32) ? rdlane(sv, r*NQ+0) : rdlane(cv, r*NQ+0);
      a *= (lane & 16) ? rdlane(sv, r*NQ+1) : rdlane(cv, r*NQ+1);
      a *= (lane &  8) ? rdlane(sv, r*NQ+2) : rdlane(cv, r*NQ+2);
      a *= (lane &  4) ? rdlane(sv, r*NQ+3) : rdlane(cv, r*NQ+3);
      a *= (lane &  2) ? rdlane(sv, r*NQ+4) : rdlane(cv, r*NQ+4);
      a *= (lane &  1) ? rdlane(sv, r*NQ+5) : rdlane(cv, r*NQ+5);
      re[r] = a;
      im[r] = 0.0f;
    }

    // ---- 3 entangling layers (ranges 1, 2, 1) ----
    layerN<0>(re, im, car, cai, cbr, cbi, sgn, pa1, lane);
    layerN<6>(re, im, car, cai, cbr, cbi, sgn, pa2, lane);
    layerN<12>(re, im, car, cai, cbr, cbi, sgn, pa1, lane);

    // ---- measurement + classifier head ----
    #pragma unroll
    for (int r = 0; r < NB; ++r) {
      const float p = fmaf(re[r], re[r], im[r] * im[r]);
      float vout = 0.0f;
      #pragma unroll
      for (int j = 0; j < 5; ++j) {
        const float o = bcast63(red_sum(p * g5[j]));
        vout = (lane == j) ? o : vout;
      }
      const int tr = t0 + r;
      if (lane < 5 && tr < B) out[(size_t)tr * 5 + lane] = vout + bcv;
    }
  }
}

extern "C" void kernel_launch(void* const* d_in, const int* in_sizes, int n_in,
                              void* d_out, int out_size, void* d_ws, size_t ws_size,
                              hipStream_t stream) {
  const float* x     = (const float*)d_in[0];
  const float* W1    = (const float*)d_in[1];
  const float* b1    = (const float*)d_in[2];
  const float* ln_g  = (const float*)d_in[3];
  const float* ln_b  = (const float*)d_in[4];
  const float* W2    = (const float*)d_in[5];
  const float* b2    = (const float*)d_in[6];
  const float* th_sh = (const float*)d_in[7];
  const float* th_tk = (const float*)d_in[8];
  const float* Wc    = (const float*)d_in[9];
  const float* bc    = (const float*)d_in[10];
  float* out = (float*)d_out;

  const int B = in_sizes[0] / DIM;
  int blocks = (B + 4 * NB - 1) / (4 * NB);
  if (blocks > 2048) blocks = 2048;
  qmaml_v4<<<blocks, 256, 0, stream>>>(x, W1, b1, ln_g, ln_b, W2, b2,
                                       th_sh, th_tk, Wc, bc, out, B);
}